// Round 2
// baseline (895.973 us; speedup 1.0000x reference)
//
#include <hip/hip_runtime.h>

#define NB    256
#define NIN   128
#define DD    256
#define NOUT  32
#define HDIM  64
#define EPS   1e-8f

// ---------------------------------------------------------------------------
// K1: u[n,i,h] = squash_h(x[n,i,:]·Wcap[i,:,h] + Bcap[i,h]);  ai[n,i] = ||u||
// Block: (i, n-chunk of 64), 256 threads, LDS-tiled GEMM [64n,256d]@[256d,64h]
// ---------------------------------------------------------------------------
__global__ __launch_bounds__(256, 2) void k_u_ai(
    const float* __restrict__ x, const float* __restrict__ Wcap,
    const float* __restrict__ Bcap, float* __restrict__ u, float* __restrict__ ai)
{
    const int i  = blockIdx.x;          // 0..127
    const int n0 = blockIdx.y * 64;     // 0,64,128,192
    const int t  = threadIdx.x;

    __shared__ float Wl[128][68];       // half of Wcap[i]: [128 d][64 h]
    __shared__ float xl[64][132];       // x tile: [64 n][128 d]

    const int tn = t >> 4, th = t & 15; // tn: n-group (4 rows), th: h-group (4 cols)
    const int h0 = th * 4;

    float acc[4][4];
    {   // init with bias
        const float4 b = *(const float4*)(Bcap + i * 64 + h0);
        #pragma unroll
        for (int r = 0; r < 4; ++r) { acc[r][0]=b.x; acc[r][1]=b.y; acc[r][2]=b.z; acc[r][3]=b.w; }
    }

    for (int half = 0; half < 2; ++half) {
        // stage W: 128x64 floats = 2048 float4
        const float4* wsrc = (const float4*)(Wcap + (size_t)i * DD * 64 + (size_t)half * 128 * 64);
        #pragma unroll
        for (int p = 0; p < 8; ++p) {
            int k = t + p * 256;
            float4 v = wsrc[k];
            int d = k >> 4, h4 = (k & 15) * 4;
            *(float4*)&Wl[d][h4] = v;
        }
        // stage x: 64 rows x 128 cols = 2048 float4
        #pragma unroll
        for (int p = 0; p < 8; ++p) {
            int k = t + p * 256;
            int row = k >> 5, c4 = (k & 31) * 4;
            float4 v = *(const float4*)(x + ((size_t)(n0 + row) * NIN + i) * DD + half * 128 + c4);
            *(float4*)&xl[row][c4] = v;
        }
        __syncthreads();
        #pragma unroll 4
        for (int d = 0; d < 128; ++d) {
            float a0 = xl[tn*4+0][d], a1 = xl[tn*4+1][d], a2 = xl[tn*4+2][d], a3 = xl[tn*4+3][d];
            float w0 = Wl[d][h0+0], w1 = Wl[d][h0+1], w2 = Wl[d][h0+2], w3 = Wl[d][h0+3];
            acc[0][0]=fmaf(a0,w0,acc[0][0]); acc[0][1]=fmaf(a0,w1,acc[0][1]); acc[0][2]=fmaf(a0,w2,acc[0][2]); acc[0][3]=fmaf(a0,w3,acc[0][3]);
            acc[1][0]=fmaf(a1,w0,acc[1][0]); acc[1][1]=fmaf(a1,w1,acc[1][1]); acc[1][2]=fmaf(a1,w2,acc[1][2]); acc[1][3]=fmaf(a1,w3,acc[1][3]);
            acc[2][0]=fmaf(a2,w0,acc[2][0]); acc[2][1]=fmaf(a2,w1,acc[2][1]); acc[2][2]=fmaf(a2,w2,acc[2][2]); acc[2][3]=fmaf(a2,w3,acc[2][3]);
            acc[3][0]=fmaf(a3,w0,acc[3][0]); acc[3][1]=fmaf(a3,w1,acc[3][1]); acc[3][2]=fmaf(a3,w2,acc[3][2]); acc[3][3]=fmaf(a3,w3,acc[3][3]);
        }
        __syncthreads();
    }

    // squash per n-row: norm over all 64 h (4 local + 16 th-lanes)
    #pragma unroll
    for (int r = 0; r < 4; ++r) {
        float s = acc[r][0]*acc[r][0] + acc[r][1]*acc[r][1] + acc[r][2]*acc[r][2] + acc[r][3]*acc[r][3];
        s += __shfl_xor(s, 1); s += __shfl_xor(s, 2); s += __shfl_xor(s, 4); s += __shfl_xor(s, 8);
        float n2 = s, nrm = sqrtf(n2);
        float f = (n2 / (n2 + 1.0f)) / (nrm + EPS);
        int n = n0 + tn * 4 + r;
        float4 ov = make_float4(f*acc[r][0], f*acc[r][1], f*acc[r][2], f*acc[r][3]);
        *(float4*)(u + ((size_t)n * NIN + i) * HDIM + h0) = ov;
        if (th == 0) ai[(size_t)n * NIN + i] = f * nrm;
    }
}

// ---------------------------------------------------------------------------
// K2: votes[nl,i,o,h] = (u[n,i,:]·Wv[i,o,:,h] + Bv[i,o,h]) * mask[n,i]
// Block: (i*32+o, n-subchunk of 64), 256 threads, [64n,64d]@[64d,64h]
// ---------------------------------------------------------------------------
__global__ __launch_bounds__(256, 4) void k_votes(
    const float* __restrict__ u, const float* __restrict__ Wv,
    const float* __restrict__ Bv, const float* __restrict__ mask,
    float* __restrict__ votes, int n0, int cnt)
{
    const int io = blockIdx.x;           // i*32+o
    const int i  = io >> 5;
    const int o  = io & 31;
    const int nbase = blockIdx.y * 64;   // within chunk
    const int t  = threadIdx.x;

    __shared__ float Wl[64][68];
    __shared__ float ul[64][68];

    // stage W slice: 64x64 = 1024 float4
    const float4* wsrc = (const float4*)(Wv + (size_t)io * 4096);
    #pragma unroll
    for (int p = 0; p < 4; ++p) {
        int k = t + p * 256;
        float4 v = wsrc[k];
        int d = k >> 4, h4 = (k & 15) * 4;
        *(float4*)&Wl[d][h4] = v;
    }
    // stage u subchunk: 64 rows x 64 d
    {
        int q = t & 15, nr0 = t >> 4;
        #pragma unroll
        for (int p = 0; p < 4; ++p) {
            int row = nr0 + p * 16;
            int nin = nbase + row;
            float4 v = make_float4(0.f, 0.f, 0.f, 0.f);
            if (nin < cnt) v = ((const float4*)(u + ((size_t)(n0 + nin) * NIN + i) * HDIM))[q];
            *(float4*)&ul[row][q * 4] = v;
        }
    }
    __syncthreads();

    const int tn = t >> 4, th = t & 15;
    const int h0 = th * 4;
    float acc[4][4];
    {
        const float4 b = *(const float4*)(Bv + (size_t)io * 64 + h0);
        #pragma unroll
        for (int r = 0; r < 4; ++r) { acc[r][0]=b.x; acc[r][1]=b.y; acc[r][2]=b.z; acc[r][3]=b.w; }
    }
    #pragma unroll 4
    for (int d = 0; d < 64; ++d) {
        float a0 = ul[tn*4+0][d], a1 = ul[tn*4+1][d], a2 = ul[tn*4+2][d], a3 = ul[tn*4+3][d];
        float w0 = Wl[d][h0+0], w1 = Wl[d][h0+1], w2 = Wl[d][h0+2], w3 = Wl[d][h0+3];
        acc[0][0]=fmaf(a0,w0,acc[0][0]); acc[0][1]=fmaf(a0,w1,acc[0][1]); acc[0][2]=fmaf(a0,w2,acc[0][2]); acc[0][3]=fmaf(a0,w3,acc[0][3]);
        acc[1][0]=fmaf(a1,w0,acc[1][0]); acc[1][1]=fmaf(a1,w1,acc[1][1]); acc[1][2]=fmaf(a1,w2,acc[1][2]); acc[1][3]=fmaf(a1,w3,acc[1][3]);
        acc[2][0]=fmaf(a2,w0,acc[2][0]); acc[2][1]=fmaf(a2,w1,acc[2][1]); acc[2][2]=fmaf(a2,w2,acc[2][2]); acc[2][3]=fmaf(a2,w3,acc[2][3]);
        acc[3][0]=fmaf(a3,w0,acc[3][0]); acc[3][1]=fmaf(a3,w1,acc[3][1]); acc[3][2]=fmaf(a3,w2,acc[3][2]); acc[3][3]=fmaf(a3,w3,acc[3][3]);
    }
    #pragma unroll
    for (int r = 0; r < 4; ++r) {
        int nin = nbase + tn * 4 + r;
        if (nin < cnt) {
            float mv = mask[(size_t)(n0 + nin) * NIN + i];
            float4 ov = make_float4(acc[r][0]*mv, acc[r][1]*mv, acc[r][2]*mv, acc[r][3]*mv);
            *(float4*)(votes + ((size_t)nin * NIN + i) * (NOUT * HDIM) + o * HDIM + h0) = ov;
        }
    }
}

// ---------------------------------------------------------------------------
// K3: full 3-iteration dynamic routing, one block per batch element n.
// 512 threads = 8 waves; wave w handles i in [w*16, w*16+16).
// Lane layout: o = lane>>1 (32 outs), g = lane&1 (h-half of 32 floats).
// votes slice / vj / vj_pre live entirely in registers; softmax over the 33
// logits is a pure in-wave shfl_xor reduce (no barriers inside the i-loop).
// ---------------------------------------------------------------------------
#define BSLOT(W, LN, J) buf[(W)][((LN) << 5) + (((J) + (LN)) & 31)]

#define LOADSLAB(DST, IDX) do {                                              \
    const float4* _p = (const float4*)(vb + (size_t)(IDX) * 2048 + base);    \
    _Pragma("unroll")                                                        \
    for (int _q = 0; _q < 8; ++_q) {                                         \
        float4 _v = _p[_q];                                                  \
        (DST)[_q*4+0]=_v.x; (DST)[_q*4+1]=_v.y;                              \
        (DST)[_q*4+2]=_v.z; (DST)[_q*4+3]=_v.w; }                            \
} while (0)

#define RBODY(V, I) do {                                                     \
    const int _i = (I);                                                      \
    float _ag = 0.f;                                                         \
    _Pragma("unroll")                                                        \
    for (int _j = 0; _j < 32; ++_j) _ag = fmaf((V)[_j], vj[_j], _ag);        \
    _ag += __shfl_xor(_ag, 1);                                               \
    float _b = bijl[_i][o] + _ag;                                            \
    if (g == 0) bijl[_i][o] = _b;                                            \
    float _m = _b;                                                           \
    _m = fmaxf(_m, __shfl_xor(_m, 1));  _m = fmaxf(_m, __shfl_xor(_m, 2));   \
    _m = fmaxf(_m, __shfl_xor(_m, 4));  _m = fmaxf(_m, __shfl_xor(_m, 8));   \
    _m = fmaxf(_m, __shfl_xor(_m, 16)); _m = fmaxf(_m, __shfl_xor(_m, 32));  \
    _m = fmaxf(_m, 0.f);                                                     \
    float _e = __expf(_b - _m);                                              \
    float _es = _e;                                                          \
    _es += __shfl_xor(_es, 1);  _es += __shfl_xor(_es, 2);                   \
    _es += __shfl_xor(_es, 4);  _es += __shfl_xor(_es, 8);                   \
    _es += __shfl_xor(_es, 16); _es += __shfl_xor(_es, 32);                  \
    float _den = 0.5f * _es + __expf(-_m);                                   \
    float _c = ai_s[_i] * _e / _den;                                         \
    _Pragma("unroll")                                                        \
    for (int _j = 0; _j < 32; ++_j) vjp[_j] = fmaf(_c, (V)[_j], vjp[_j]);    \
} while (0)

#define RMERGE(WRITEOUT) do {                                                \
    __syncthreads();                                                         \
    _Pragma("unroll")                                                        \
    for (int _j = 0; _j < 32; ++_j) BSLOT(wv, lane, _j) = vjp[_j];           \
    __syncthreads();                                                         \
    if (wv == 0) {                                                           \
        float _tot[32];                                                      \
        _Pragma("unroll")                                                    \
        for (int _j = 0; _j < 32; ++_j) {                                    \
            float _s = 0.f;                                                  \
            _Pragma("unroll")                                                \
            for (int _w = 0; _w < 8; ++_w) _s += BSLOT(_w, lane, _j);        \
            _tot[_j] = _s; }                                                 \
        float _ss = 0.f;                                                     \
        _Pragma("unroll")                                                    \
        for (int _j = 0; _j < 32; ++_j) _ss = fmaf(_tot[_j], _tot[_j], _ss); \
        _ss += __shfl_xor(_ss, 1);                                           \
        float _nr = sqrtf(_ss);                                              \
        float _f = (_ss / (_ss + 1.0f)) / (_nr + EPS);                       \
        _Pragma("unroll")                                                    \
        for (int _j = 0; _j < 32; ++_j) { vj[_j] = _f * _tot[_j]; BSLOT(0, lane, _j) = vj[_j]; } \
        if (WRITEOUT) {                                                      \
            _Pragma("unroll")                                                \
            for (int _j = 0; _j < 32; ++_j)                                  \
                out[((size_t)n * NOUT + o) * HDIM + g * 32 + _j] = vj[_j];   \
        }                                                                    \
    }                                                                        \
    __syncthreads();                                                         \
    if (wv != 0) {                                                           \
        _Pragma("unroll")                                                    \
        for (int _j = 0; _j < 32; ++_j) vj[_j] = BSLOT(0, lane, _j);         \
    }                                                                        \
} while (0)

__global__ __launch_bounds__(512, 2) void k_route(
    const float* __restrict__ votes, const float* __restrict__ ai,
    float* __restrict__ out, int n0, int cnt)
{
    const int nl = blockIdx.x;
    const int n  = n0 + nl;
    const int t  = threadIdx.x;
    const int wv = t >> 6;
    const int lane = t & 63;
    const int o = lane >> 1;
    const int g = lane & 1;
    const int base = o * HDIM + g * 32;

    __shared__ float bijl[NIN][NOUT + 1];
    __shared__ float ai_s[NIN];
    __shared__ float buf[8][2048];

    if (t < NIN) ai_s[t] = ai[(size_t)n * NIN + t];
    for (int idx = t; idx < NIN * (NOUT + 1); idx += 512) ((float*)bijl)[idx] = 0.f;
    __syncthreads();

    const float* vb = votes + (size_t)nl * (NIN * NOUT * HDIM);

    float vj[32], vjp[32], cur[32], nxt[32];

    // ---- pass 1: uniform coupling c = ai/33 ----
    #pragma unroll
    for (int j = 0; j < 32; ++j) vjp[j] = 0.f;
    LOADSLAB(cur, wv * 16);
    #pragma unroll
    for (int k = 0; k < 16; k += 2) {
        LOADSLAB(nxt, wv * 16 + k + 1);
        {
            float c = ai_s[wv * 16 + k] * (1.0f / 33.0f);
            #pragma unroll
            for (int j = 0; j < 32; ++j) vjp[j] = fmaf(c, cur[j], vjp[j]);
        }
        if (k + 2 < 16) LOADSLAB(cur, wv * 16 + k + 2);
        {
            float c = ai_s[wv * 16 + k + 1] * (1.0f / 33.0f);
            #pragma unroll
            for (int j = 0; j < 32; ++j) vjp[j] = fmaf(c, nxt[j], vjp[j]);
        }
    }
    RMERGE(false);

    // ---- passes 2 & 3: agree -> bij update -> softmax -> accumulate ----
    for (int pass = 0; pass < 2; ++pass) {
        #pragma unroll
        for (int j = 0; j < 32; ++j) vjp[j] = 0.f;
        LOADSLAB(cur, wv * 16);
        #pragma unroll
        for (int k = 0; k < 16; k += 2) {
            LOADSLAB(nxt, wv * 16 + k + 1);
            RBODY(cur, wv * 16 + k);
            if (k + 2 < 16) LOADSLAB(cur, wv * 16 + k + 2);
            RBODY(nxt, wv * 16 + k + 1);
        }
        RMERGE(pass == 1);
    }
}

// ---------------------------------------------------------------------------
extern "C" void kernel_launch(void* const* d_in, const int* in_sizes, int n_in,
                              void* d_out, int out_size, void* d_ws, size_t ws_size,
                              hipStream_t stream)
{
    const float* x    = (const float*)d_in[0];
    const float* mask = (const float*)d_in[1];
    const float* Wcap = (const float*)d_in[2];
    const float* Bcap = (const float*)d_in[3];
    const float* Wv   = (const float*)d_in[4];
    const float* Bv   = (const float*)d_in[5];
    float* out = (float*)d_out;

    char* ws = (char*)d_ws;
    float* u     = (float*)ws;                     // 256*128*64*4 = 8,388,608 B
    float* ai    = (float*)(ws + 8388608);         // 256*128*4   =   131,072 B
    float* votes = (float*)(ws + 8519680);         // chunk * 1,048,576 B

    size_t avail = ws_size > 8519680 ? ws_size - 8519680 : 0;
    int chunk = 256;
    while (chunk > 4 && (size_t)chunk * 1048576ull > avail) chunk >>= 1;

    // K1: u + ai
    k_u_ai<<<dim3(NIN, 4), 256, 0, stream>>>(x, Wcap, Bcap, u, ai);

    for (int c0 = 0; c0 < NB; c0 += chunk) {
        int cnt = (NB - c0) < chunk ? (NB - c0) : chunk;
        dim3 g2(NIN * NOUT, (cnt + 63) / 64);
        k_votes<<<g2, 256, 0, stream>>>(u, Wv, Bv, mask, votes, c0, cnt);
        k_route<<<cnt, 512, 0, stream>>>(votes, ai, out, c0, cnt);
    }
}